// Round 6
// baseline (748.434 us; speedup 1.0000x reference)
//
#include <hip/hip_runtime.h>

// Problem constants: B=128, N=1024, D=8, S=64
constexpr int B   = 128;
constexpr int N   = 1024;
constexpr int DS  = 512;            // D*S, contiguous innermost per (b,n)
constexpr int NC  = 8;              // n-chunk per block
constexpr int NCH = N / NC;         // 128 chunks
constexpr int BQ  = 4;              // b's per block (one per wave)
constexpr int NBQ = B / BQ;         // 32 b-quads

typedef float f32x4 __attribute__((ext_vector_type(4)));

// Fused kernel: block = (b-quad, n-chunk), epilogue via "last block per chunk".
// R4/R5 lesson (errors 23/128, 22/128): with ctr poisoned to 0xAA..A (residue
// 10 mod 32), the (old+1)%32==0 trigger fired on arrival 22, not 32 -- the
// counter MUST start at 0 mod 32. ctr is now zeroed by a hipMemsetAsync node
// each call (graph-capturable; each call adds exactly 32 per chunk, so the
// trigger is genuinely the last arrival). Cross-block partials move via
// atomic RMWs (device-scope coherent, guide m20).
__global__ __launch_bounds__(256) void mpjrd_fused_kernel(
    const float* __restrict__ x,       // [B,N,DS]
    const float* __restrict__ W,       // [N,DS]
    const float* __restrict__ theta,   // [N]
    const float* __restrict__ r_hat,   // [N]
    float*       __restrict__ out,     // spikes[B,N] | rates[N] | thetas[N] | r_hats[N]
    float*       __restrict__ partial, // ws: [NBQ][N]
    int*         __restrict__ ctr)     // ws: [NCH], zeroed each call
{
    __shared__ float Wl[NC * DS];      // 16 KB W tile
    __shared__ float thl[NC];
    __shared__ float s_cnt[BQ][NC];
    __shared__ int   s_last;

    const int tid  = threadIdx.x;
    const int lane = tid & 63;
    const int g    = tid >> 6;                 // wave in block = b within quad
    const int nc   = blockIdx.x & (NCH - 1);
    const int bq   = blockIdx.x >> 7;
    const int n0   = nc * NC;
    const int b    = bq * BQ + g;

    // Stage W tile: 4096 floats = 1024 float4, coalesced.
    {
        const f32x4* Wg = reinterpret_cast<const f32x4*>(W + (size_t)n0 * DS);
        f32x4* Wd = reinterpret_cast<f32x4*>(Wl);
        #pragma unroll
        for (int r = 0; r < 4; ++r) Wd[tid + r * 256] = Wg[tid + r * 256];
        if (tid < NC) thl[tid] = theta[n0 + tid];
    }
    __syncthreads();

    const float* xp0 = x + ((size_t)b * N + n0) * DS + (size_t)lane * 4;

    // 8 per-lane fp64 partial dots (no shuffles inside the streaming loop).
    double a[NC];
    #pragma unroll
    for (int j = 0; j < NC; ++j) {
        const float* xp = xp0 + (size_t)j * DS;
        const f32x4 x0 = __builtin_nontemporal_load(reinterpret_cast<const f32x4*>(xp));
        const f32x4 x1 = __builtin_nontemporal_load(reinterpret_cast<const f32x4*>(xp + 256));
        const f32x4 wa = *reinterpret_cast<const f32x4*>(Wl + j * DS + lane * 4);
        const f32x4 wb = *reinterpret_cast<const f32x4*>(Wl + j * DS + lane * 4 + 256);
        // fp64 accumulation: fp32*fp32 exact in fp64 -> threshold decisions
        // bit-stable vs the numpy reference (spikes absmax 0.0 in R1-R5).
        double p0 = (double)x0.x * (double)wa.x;
        p0 += (double)x0.y * (double)wa.y;
        p0 += (double)x0.z * (double)wa.z;
        p0 += (double)x0.w * (double)wa.w;
        double p1 = (double)x1.x * (double)wb.x;
        p1 += (double)x1.y * (double)wb.y;
        p1 += (double)x1.z * (double)wb.z;
        p1 += (double)x1.w * (double)wb.w;
        a[j] = p0 + p1;
    }

    // Joint reduce-scatter: 64 lanes x 8 values -> each lane one total.
    // After stage C, lane holds j = 4*(lane&1) + 2*((lane>>1)&1) + ((lane>>2)&1).
    const bool h1 = lane & 1;
    double b0 = (h1 ? a[4] : a[0]) + __shfl_xor(h1 ? a[0] : a[4], 1);
    double b1 = (h1 ? a[5] : a[1]) + __shfl_xor(h1 ? a[1] : a[5], 1);
    double b2 = (h1 ? a[6] : a[2]) + __shfl_xor(h1 ? a[2] : a[6], 1);
    double b3 = (h1 ? a[7] : a[3]) + __shfl_xor(h1 ? a[3] : a[7], 1);
    const bool h2 = lane & 2;
    double c0 = (h2 ? b2 : b0) + __shfl_xor(h2 ? b0 : b2, 2);
    double c1 = (h2 ? b3 : b1) + __shfl_xor(h2 ? b1 : b3, 2);
    const bool h4 = lane & 4;
    double d0 = (h4 ? c1 : c0) + __shfl_xor(h4 ? c0 : c1, 4);
    d0 += __shfl_xor(d0, 8);
    d0 += __shfl_xor(d0, 16);
    d0 += __shfl_xor(d0, 32);

    const int j = 4 * (lane & 1) + 2 * ((lane >> 1) & 1) + ((lane >> 2) & 1);
    if (lane < 8) {
        const float s = (d0 >= (double)thl[j]) ? 1.0f : 0.0f;
        out[(size_t)b * N + n0 + j] = s;   // 8 dwords in 32 B: one transaction
        s_cnt[g][j] = s;
    }
    __syncthreads();
    if (tid < NC) {
        const float cnt = s_cnt[0][tid] + s_cnt[1][tid] + s_cnt[2][tid] + s_cnt[3][tid];
        // Device-scope coherent write (cross-XCD visible), full overwrite each call.
        atomicExch(&partial[(size_t)bq * N + n0 + tid], cnt);
    }
    __threadfence();
    __syncthreads();
    if (tid == 0) {
        const int old = atomicAdd(&ctr[nc], 1);
        s_last = (old == NBQ - 1) ? 1 : 0;   // ctr starts at 0: last arrival only
    }
    __syncthreads();

    if (s_last) {
        __threadfence();
        // thread t: bq' = t&31, neuron jn = t>>5 (8 n x 32 partials).
        // Coherent read via atomic RMW (+0.0f).
        float v = atomicAdd(&partial[(size_t)(tid & 31) * N + n0 + (tid >> 5)], 0.0f);
        #pragma unroll
        for (int off = 16; off > 0; off >>= 1) v += __shfl_down(v, off, 32);
        if ((lane & 31) == 0) {
            const int n = n0 + (tid >> 5);
            const float rate = v * (1.0f / 128.0f);
            const float rh   = 0.95f * r_hat[n] + 0.05f * rate;  // EMA
            const float th   = theta[n] + 0.1f * (rh - 0.1f);    // adaptation
            out[(size_t)B * N + n]         = rate;
            out[(size_t)B * N + N + n]     = th;
            out[(size_t)B * N + 2 * N + n] = rh;
        }
    }
}

extern "C" void kernel_launch(void* const* d_in, const int* in_sizes, int n_in,
                              void* d_out, int out_size, void* d_ws, size_t ws_size,
                              hipStream_t stream) {
    const float* x     = (const float*)d_in[0];
    const float* W     = (const float*)d_in[1];
    const float* theta = (const float*)d_in[2];
    const float* r_hat = (const float*)d_in[3];
    float* out     = (float*)d_out;
    float* partial = (float*)d_ws;                        // 128 KB, fully overwritten (atomicExch)
    int*   ctr     = (int*)((char*)d_ws + NBQ * N * 4);   // [NCH]

    // ctr must start at 0 so the last-arrival test is exact (R4/R5 bug).
    hipMemsetAsync(ctr, 0, NCH * sizeof(int), stream);
    mpjrd_fused_kernel<<<NBQ * NCH, 256, 0, stream>>>(x, W, theta, r_hat, out, partial, ctr);
}

// Round 7
// 55.052 us; speedup vs baseline: 13.5950x; 13.5950x over previous
//
#include <hip/hip_runtime.h>

// Problem constants: B=128, N=1024, D=8, S=64
constexpr int B   = 128;
constexpr int N   = 1024;
constexpr int DS  = 512;            // D*S, contiguous innermost per (b,n)
constexpr int NC  = 8;              // n-chunk per block
constexpr int NCH = N / NC;         // 128 chunks
constexpr int BQ  = 4;              // b's per block (one per wave)
constexpr int NBQ = B / BQ;         // 32 b-quads

typedef float f32x4 __attribute__((ext_vector_type(4)));

// Fused kernel, FENCE-FREE cross-block handshake.
// R6 lesson: __threadfence() on gfx950 = L2 writeback+invalidate per wave ->
// 16x regression (762us, VALUBusy 1.1%). Atomic RMWs alone are device-scope
// coherent (m20; ctr worked in every round). Ordering is enforced by DATA
// DEPENDENCY: the counts-atomicAdd's returned old value (s_waitcnt'd by the
// compiler) flows through LDS into the ctr increment, so the counts RMW has
// completed at the coherence point before ctr is bumped. The finalizer that
// sees ctr hit 32 reads counts with atomicAdd(+0): same-address RMWs
// serialize at the coherence point, so it must observe all completed adds.
__global__ __launch_bounds__(256) void mpjrd_fused_kernel(
    const float* __restrict__ x,       // [B,N,DS]
    const float* __restrict__ W,       // [N,DS]
    const float* __restrict__ theta,   // [N]
    const float* __restrict__ r_hat,   // [N]
    float*       __restrict__ out,     // spikes[B,N] | rates[N] | thetas[N] | r_hats[N]
    int*         __restrict__ counts,  // ws: [N], zeroed each call
    int*         __restrict__ ctr)     // ws: [NCH], zeroed each call
{
    __shared__ float Wl[NC * DS];      // 16 KB W tile
    __shared__ float thl[NC];
    __shared__ int   s_cnt[BQ][NC];
    __shared__ int   s_dep[NC];
    __shared__ int   s_last;

    const int tid  = threadIdx.x;
    const int lane = tid & 63;
    const int g    = tid >> 6;                 // wave in block = b within quad
    const int nc   = blockIdx.x & (NCH - 1);
    const int bq   = blockIdx.x >> 7;
    const int n0   = nc * NC;
    const int b    = bq * BQ + g;

    // Stage W tile: 4096 floats = 1024 float4, coalesced.
    {
        const f32x4* Wg = reinterpret_cast<const f32x4*>(W + (size_t)n0 * DS);
        f32x4* Wd = reinterpret_cast<f32x4*>(Wl);
        #pragma unroll
        for (int r = 0; r < 4; ++r) Wd[tid + r * 256] = Wg[tid + r * 256];
        if (tid < NC) thl[tid] = theta[n0 + tid];
    }
    __syncthreads();

    const float* xp0 = x + ((size_t)b * N + n0) * DS + (size_t)lane * 4;

    // 8 per-lane fp64 partial dots (no shuffles inside the streaming loop).
    double a[NC];
    #pragma unroll
    for (int j = 0; j < NC; ++j) {
        const float* xp = xp0 + (size_t)j * DS;
        const f32x4 x0 = __builtin_nontemporal_load(reinterpret_cast<const f32x4*>(xp));
        const f32x4 x1 = __builtin_nontemporal_load(reinterpret_cast<const f32x4*>(xp + 256));
        const f32x4 wa = *reinterpret_cast<const f32x4*>(Wl + j * DS + lane * 4);
        const f32x4 wb = *reinterpret_cast<const f32x4*>(Wl + j * DS + lane * 4 + 256);
        // fp64 accumulation: fp32*fp32 exact in fp64 -> threshold decisions
        // bit-stable vs the numpy reference (spikes absmax 0.0 in R1-R6).
        double p0 = (double)x0.x * (double)wa.x;
        p0 += (double)x0.y * (double)wa.y;
        p0 += (double)x0.z * (double)wa.z;
        p0 += (double)x0.w * (double)wa.w;
        double p1 = (double)x1.x * (double)wb.x;
        p1 += (double)x1.y * (double)wb.y;
        p1 += (double)x1.z * (double)wb.z;
        p1 += (double)x1.w * (double)wb.w;
        a[j] = p0 + p1;
    }

    // Joint reduce-scatter: 64 lanes x 8 values -> each lane one total.
    // After stage C, lane holds j = 4*(lane&1) + 2*((lane>>1)&1) + ((lane>>2)&1).
    const bool h1 = lane & 1;
    double b0 = (h1 ? a[4] : a[0]) + __shfl_xor(h1 ? a[0] : a[4], 1);
    double b1 = (h1 ? a[5] : a[1]) + __shfl_xor(h1 ? a[1] : a[5], 1);
    double b2 = (h1 ? a[6] : a[2]) + __shfl_xor(h1 ? a[2] : a[6], 1);
    double b3 = (h1 ? a[7] : a[3]) + __shfl_xor(h1 ? a[3] : a[7], 1);
    const bool h2 = lane & 2;
    double c0 = (h2 ? b2 : b0) + __shfl_xor(h2 ? b0 : b2, 2);
    double c1 = (h2 ? b3 : b1) + __shfl_xor(h2 ? b1 : b3, 2);
    const bool h4 = lane & 4;
    double d0 = (h4 ? c1 : c0) + __shfl_xor(h4 ? c0 : c1, 4);
    d0 += __shfl_xor(d0, 8);
    d0 += __shfl_xor(d0, 16);
    d0 += __shfl_xor(d0, 32);

    const int j = 4 * (lane & 1) + 2 * ((lane >> 1) & 1) + ((lane >> 2) & 1);
    if (lane < 8) {
        const int s = (d0 >= (double)thl[j]) ? 1 : 0;
        out[(size_t)b * N + n0 + j] = (float)s;   // 8 dwords in 32 B: one transaction
        s_cnt[g][j] = s;
    }
    __syncthreads();

    if (tid < NC) {
        const int cnt = s_cnt[0][tid] + s_cnt[1][tid] + s_cnt[2][tid] + s_cnt[3][tid];
        // Device-coherent accumulate; returned old value creates the ordering dep.
        const int old = atomicAdd(&counts[n0 + tid], cnt);
        s_dep[tid] = old >> 8;   // always 0 (old <= 128), but compiler must wait for it
    }
    __syncthreads();

    if (tid == 0) {
        // Increment is 1 + 0: data-depends on all 8 counts-RMW completions.
        const int extra = s_dep[0] + s_dep[1] + s_dep[2] + s_dep[3] +
                          s_dep[4] + s_dep[5] + s_dep[6] + s_dep[7];
        const int old2 = atomicAdd(&ctr[nc], 1 + extra);
        s_last = (old2 == NBQ - 1) ? 1 : 0;   // ctr zeroed each call: true last arrival
    }
    __syncthreads();

    if (s_last && tid < NC) {
        const int n = n0 + tid;
        // Coherent read via same-address RMW: sees every completed add.
        const int c = atomicAdd(&counts[n], 0);
        const float rate = (float)c * (1.0f / 128.0f);
        const float rh   = 0.95f * r_hat[n] + 0.05f * rate;  // (1-ALPHA)*r_hat + ALPHA*rate
        const float th   = theta[n] + 0.1f * (rh - 0.1f);    // theta + THETA_LR*(rh - R_TARGET)
        out[(size_t)B * N + n]         = rate;
        out[(size_t)B * N + N + n]     = th;
        out[(size_t)B * N + 2 * N + n] = rh;
    }
}

extern "C" void kernel_launch(void* const* d_in, const int* in_sizes, int n_in,
                              void* d_out, int out_size, void* d_ws, size_t ws_size,
                              hipStream_t stream) {
    const float* x     = (const float*)d_in[0];
    const float* W     = (const float*)d_in[1];
    const float* theta = (const float*)d_in[2];
    const float* r_hat = (const float*)d_in[3];
    float* out    = (float*)d_out;
    int*   counts = (int*)d_ws;                       // [N]
    int*   ctr    = (int*)((char*)d_ws + N * 4);      // [NCH]

    // counts and ctr are contiguous: one small memset node (4.6 KB) zeroes both.
    hipMemsetAsync(d_ws, 0, (N + NCH) * sizeof(int), stream);
    mpjrd_fused_kernel<<<NBQ * NCH, 256, 0, stream>>>(x, W, theta, r_hat, out, counts, ctr);
}

// Round 8
// 46.895 us; speedup vs baseline: 15.9599x; 1.1739x over previous
//
#include <hip/hip_runtime.h>

// Problem constants: B=128, N=1024, D=8, S=64
constexpr int B   = 128;
constexpr int N   = 1024;
constexpr int DS  = 512;            // D*S, contiguous innermost per (b,n)
constexpr int NC  = 8;              // n-chunk per block
constexpr int NCH = N / NC;         // 128 chunks
constexpr int BQ  = 4;              // b's per block (one per wave)
constexpr int NBQ = B / BQ;         // 32 b-quads

typedef float f32x4 __attribute__((ext_vector_type(4)));

// R8 = R3's proven 2-kernel structure + R4's (now correctness-validated) joint
// reduce-scatter. Lessons baked in:
//   R6: __threadfence = per-wave L2 writeback/inv on gfx950 -> 16x regression. NONE here.
//   R7: fused handshake (atomic round-trips in every block's tail) costs more
//       than a second dispatch. Cross-block data -> plain stores + kernel boundary.
//   R4-R7: joint reduce-scatter lane mapping verified exact (spikes absmax 0.0).
// Kernel 1: block = (b-quad, n-chunk); wave streams 16 KB x contiguously; all
// 16 loads issue before any reduction (deep HBM pipeline); ONE joint
// reduce-scatter (10 double-shuffles) replaces 48 per-n shuffles.
__global__ __launch_bounds__(256) void mpjrd_spike_kernel(
    const float* __restrict__ x,       // [B,N,DS]
    const float* __restrict__ W,       // [N,DS]
    const float* __restrict__ theta,   // [N]
    float*       __restrict__ out,     // spikes[B,N] | rates[N] | thetas[N] | r_hats[N]
    float*       __restrict__ partial) // ws: [NBQ][N]
{
    __shared__ float Wl[NC * DS];      // 16 KB W tile
    __shared__ float thl[NC];
    __shared__ float s_cnt[BQ][NC];

    const int tid  = threadIdx.x;
    const int lane = tid & 63;
    const int g    = tid >> 6;                 // wave in block = b within quad
    const int nc   = blockIdx.x & (NCH - 1);
    const int bq   = blockIdx.x >> 7;
    const int n0   = nc * NC;
    const int b    = bq * BQ + g;

    // Stage W tile: 4096 floats = 1024 float4, coalesced.
    {
        const f32x4* Wg = reinterpret_cast<const f32x4*>(W + (size_t)n0 * DS);
        f32x4* Wd = reinterpret_cast<f32x4*>(Wl);
        #pragma unroll
        for (int r = 0; r < 4; ++r) Wd[tid + r * 256] = Wg[tid + r * 256];
        if (tid < NC) thl[tid] = theta[n0 + tid];
    }
    __syncthreads();

    const float* xp0 = x + ((size_t)b * N + n0) * DS + (size_t)lane * 4;

    // 8 per-lane fp64 partial dots; no cross-lane ops inside the streaming loop.
    double a[NC];
    #pragma unroll
    for (int j = 0; j < NC; ++j) {
        const float* xp = xp0 + (size_t)j * DS;
        const f32x4 x0 = __builtin_nontemporal_load(reinterpret_cast<const f32x4*>(xp));
        const f32x4 x1 = __builtin_nontemporal_load(reinterpret_cast<const f32x4*>(xp + 256));
        const f32x4 wa = *reinterpret_cast<const f32x4*>(Wl + j * DS + lane * 4);
        const f32x4 wb = *reinterpret_cast<const f32x4*>(Wl + j * DS + lane * 4 + 256);
        // fp64 accumulation: fp32*fp32 exact in fp64 -> threshold decisions
        // bit-stable vs the numpy reference (spikes absmax 0.0 in R1-R7).
        double p0 = (double)x0.x * (double)wa.x;
        p0 += (double)x0.y * (double)wa.y;
        p0 += (double)x0.z * (double)wa.z;
        p0 += (double)x0.w * (double)wa.w;
        double p1 = (double)x1.x * (double)wb.x;
        p1 += (double)x1.y * (double)wb.y;
        p1 += (double)x1.z * (double)wb.z;
        p1 += (double)x1.w * (double)wb.w;
        a[j] = p0 + p1;
    }

    // Joint reduce-scatter: 64 lanes x 8 values -> each lane one total.
    // After stage C, lane holds j = 4*(lane&1) + 2*((lane>>1)&1) + ((lane>>2)&1).
    const bool h1 = lane & 1;
    double b0 = (h1 ? a[4] : a[0]) + __shfl_xor(h1 ? a[0] : a[4], 1);
    double b1 = (h1 ? a[5] : a[1]) + __shfl_xor(h1 ? a[1] : a[5], 1);
    double b2 = (h1 ? a[6] : a[2]) + __shfl_xor(h1 ? a[2] : a[6], 1);
    double b3 = (h1 ? a[7] : a[3]) + __shfl_xor(h1 ? a[3] : a[7], 1);
    const bool h2 = lane & 2;
    double c0 = (h2 ? b2 : b0) + __shfl_xor(h2 ? b0 : b2, 2);
    double c1 = (h2 ? b3 : b1) + __shfl_xor(h2 ? b1 : b3, 2);
    const bool h4 = lane & 4;
    double d0 = (h4 ? c1 : c0) + __shfl_xor(h4 ? c0 : c1, 4);
    d0 += __shfl_xor(d0, 8);
    d0 += __shfl_xor(d0, 16);
    d0 += __shfl_xor(d0, 32);

    const int j = 4 * (lane & 1) + 2 * ((lane >> 1) & 1) + ((lane >> 2) & 1);
    if (lane < 8) {
        const float s = (d0 >= (double)thl[j]) ? 1.0f : 0.0f;
        out[(size_t)b * N + n0 + j] = s;   // 8 dwords in 32 B: one transaction
        s_cnt[g][j] = s;
    }
    __syncthreads();
    if (tid < NC) {
        // Plain store; visibility to k2 is guaranteed by the kernel boundary (R1-R3 proven).
        partial[(size_t)bq * N + n0 + tid] =
            s_cnt[0][tid] + s_cnt[1][tid] + s_cnt[2][tid] + s_cnt[3][tid];
    }
}

// Kernel 2: thread per neuron; sum 32 quad-partials (coalesced), emit epilogue.
__global__ __launch_bounds__(256) void mpjrd_finalize_kernel(
    const float* __restrict__ partial,
    const float* __restrict__ theta,
    const float* __restrict__ r_hat,
    float*       __restrict__ out)
{
    const int n = blockIdx.x * 256 + threadIdx.x;
    float c = 0.0f;
    #pragma unroll
    for (int i = 0; i < NBQ; ++i) c += partial[(size_t)i * N + n];
    const float rate = c * (1.0f / 128.0f);
    const float rh   = 0.95f * r_hat[n] + 0.05f * rate;  // (1-ALPHA)*r_hat + ALPHA*rate
    const float th   = theta[n] + 0.1f * (rh - 0.1f);    // theta + THETA_LR*(rh - R_TARGET)
    out[(size_t)B * N + n]         = rate;
    out[(size_t)B * N + N + n]     = th;
    out[(size_t)B * N + 2 * N + n] = rh;
}

extern "C" void kernel_launch(void* const* d_in, const int* in_sizes, int n_in,
                              void* d_out, int out_size, void* d_ws, size_t ws_size,
                              hipStream_t stream) {
    const float* x     = (const float*)d_in[0];
    const float* W     = (const float*)d_in[1];
    const float* theta = (const float*)d_in[2];
    const float* r_hat = (const float*)d_in[3];
    float* out     = (float*)d_out;
    float* partial = (float*)d_ws;   // NBQ*N floats = 128 KB, fully written each call

    mpjrd_spike_kernel<<<NBQ * NCH, 256, 0, stream>>>(x, W, theta, out, partial);
    mpjrd_finalize_kernel<<<N / 256, 256, 0, stream>>>(partial, theta, r_hat, out);
}

// Round 9
// 45.745 us; speedup vs baseline: 16.3611x; 1.0251x over previous
//
#include <hip/hip_runtime.h>

// Problem constants: B=128, N=1024, D=8, S=64
constexpr int B   = 128;
constexpr int N   = 1024;
constexpr int DS  = 512;            // D*S, contiguous innermost per (b,n)
constexpr int NC  = 16;             // n-chunk per block (R9: 8 -> 16, 32 KB runs/wave)
constexpr int NCH = N / NC;         // 64 chunks
constexpr int BQ  = 4;              // b's per block (one per wave)
constexpr int NBQ = B / BQ;         // 32 b-quads

typedef float f32x4 __attribute__((ext_vector_type(4)));

// R9 = R8 with NC=16: each wave streams 32 KB of x CONTIGUOUSLY (16 n of one
// b). W tile 32 KB in LDS -> 4 blocks/CU, 16 waves/CU, 512 outstanding
// loads/CU (same MLP as R8's 32 waves x 16 loads). Joint reduce-scatter
// extended to 16 values (same validated recursion; j = 8b0+4b1+2b2+b3).
// Lessons kept: no fences (R6), no fused handshake (R7), plain stores +
// kernel boundary for cross-block data (R1-R3, R8).
__global__ __launch_bounds__(256) void mpjrd_spike_kernel(
    const float* __restrict__ x,       // [B,N,DS]
    const float* __restrict__ W,       // [N,DS]
    const float* __restrict__ theta,   // [N]
    float*       __restrict__ out,     // spikes[B,N] | rates[N] | thetas[N] | r_hats[N]
    float*       __restrict__ partial) // ws: [NBQ][N]
{
    __shared__ float Wl[NC * DS];      // 32 KB W tile
    __shared__ float thl[NC];
    __shared__ float s_cnt[BQ][NC];

    const int tid  = threadIdx.x;
    const int lane = tid & 63;
    const int g    = tid >> 6;                 // wave in block = b within quad
    const int nc   = blockIdx.x & (NCH - 1);
    const int bq   = blockIdx.x >> 6;          // blockIdx / NCH
    const int n0   = nc * NC;
    const int b    = bq * BQ + g;

    // Stage W tile: 8192 floats = 2048 float4, 8 per thread, coalesced.
    {
        const f32x4* Wg = reinterpret_cast<const f32x4*>(W + (size_t)n0 * DS);
        f32x4* Wd = reinterpret_cast<f32x4*>(Wl);
        #pragma unroll
        for (int r = 0; r < 8; ++r) Wd[tid + r * 256] = Wg[tid + r * 256];
        if (tid < NC) thl[tid] = theta[n0 + tid];
    }
    __syncthreads();

    const float* xp0 = x + ((size_t)b * N + n0) * DS + (size_t)lane * 4;

    // 16 per-lane fp64 partial dots; no cross-lane ops in the streaming loop.
    double a[NC];
    #pragma unroll
    for (int j = 0; j < NC; ++j) {
        const float* xp = xp0 + (size_t)j * DS;
        const f32x4 x0 = __builtin_nontemporal_load(reinterpret_cast<const f32x4*>(xp));
        const f32x4 x1 = __builtin_nontemporal_load(reinterpret_cast<const f32x4*>(xp + 256));
        const f32x4 wa = *reinterpret_cast<const f32x4*>(Wl + j * DS + lane * 4);
        const f32x4 wb = *reinterpret_cast<const f32x4*>(Wl + j * DS + lane * 4 + 256);
        // fp64 accumulation: fp32*fp32 exact in fp64 -> threshold decisions
        // bit-stable vs the numpy reference (spikes absmax 0.0 in R1-R8).
        double p0 = (double)x0.x * (double)wa.x;
        p0 += (double)x0.y * (double)wa.y;
        p0 += (double)x0.z * (double)wa.z;
        p0 += (double)x0.w * (double)wa.w;
        double p1 = (double)x1.x * (double)wb.x;
        p1 += (double)x1.y * (double)wb.y;
        p1 += (double)x1.z * (double)wb.z;
        p1 += (double)x1.w * (double)wb.w;
        a[j] = p0 + p1;
    }

    // Joint reduce-scatter: 64 lanes x 16 values -> lane (l&15) owns
    // j = 8*(l&1) + 4*((l>>1)&1) + 2*((l>>2)&1) + ((l>>3)&1).
    const bool h1 = lane & 1;
    double r1[8];
    #pragma unroll
    for (int k = 0; k < 8; ++k)
        r1[k] = (h1 ? a[k + 8] : a[k]) + __shfl_xor(h1 ? a[k] : a[k + 8], 1);
    const bool h2 = lane & 2;
    double r2[4];
    #pragma unroll
    for (int k = 0; k < 4; ++k)
        r2[k] = (h2 ? r1[k + 4] : r1[k]) + __shfl_xor(h2 ? r1[k] : r1[k + 4], 2);
    const bool h4 = lane & 4;
    double r3[2];
    #pragma unroll
    for (int k = 0; k < 2; ++k)
        r3[k] = (h4 ? r2[k + 2] : r2[k]) + __shfl_xor(h4 ? r2[k] : r2[k + 2], 4);
    const bool h8 = lane & 8;
    double e = (h8 ? r3[1] : r3[0]) + __shfl_xor(h8 ? r3[0] : r3[1], 8);
    e += __shfl_xor(e, 16);
    e += __shfl_xor(e, 32);

    const int j = 8 * (lane & 1) + 4 * ((lane >> 1) & 1) +
                  2 * ((lane >> 2) & 1) + ((lane >> 3) & 1);
    if (lane < NC) {
        const float s = (e >= (double)thl[j]) ? 1.0f : 0.0f;
        out[(size_t)b * N + n0 + j] = s;   // 16 dwords in 64 B: one transaction
        s_cnt[g][j] = s;
    }
    __syncthreads();
    if (tid < NC) {
        // Plain store; visibility to k2 guaranteed by the kernel boundary.
        partial[(size_t)bq * N + n0 + tid] =
            s_cnt[0][tid] + s_cnt[1][tid] + s_cnt[2][tid] + s_cnt[3][tid];
    }
}

// Kernel 2: thread per neuron; sum 32 quad-partials (coalesced), emit epilogue.
__global__ __launch_bounds__(256) void mpjrd_finalize_kernel(
    const float* __restrict__ partial,
    const float* __restrict__ theta,
    const float* __restrict__ r_hat,
    float*       __restrict__ out)
{
    const int n = blockIdx.x * 256 + threadIdx.x;
    float c = 0.0f;
    #pragma unroll
    for (int i = 0; i < NBQ; ++i) c += partial[(size_t)i * N + n];
    const float rate = c * (1.0f / 128.0f);
    const float rh   = 0.95f * r_hat[n] + 0.05f * rate;  // (1-ALPHA)*r_hat + ALPHA*rate
    const float th   = theta[n] + 0.1f * (rh - 0.1f);    // theta + THETA_LR*(rh - R_TARGET)
    out[(size_t)B * N + n]         = rate;
    out[(size_t)B * N + N + n]     = th;
    out[(size_t)B * N + 2 * N + n] = rh;
}

extern "C" void kernel_launch(void* const* d_in, const int* in_sizes, int n_in,
                              void* d_out, int out_size, void* d_ws, size_t ws_size,
                              hipStream_t stream) {
    const float* x     = (const float*)d_in[0];
    const float* W     = (const float*)d_in[1];
    const float* theta = (const float*)d_in[2];
    const float* r_hat = (const float*)d_in[3];
    float* out     = (float*)d_out;
    float* partial = (float*)d_ws;   // NBQ*N floats = 128 KB, fully written each call

    mpjrd_spike_kernel<<<NBQ * NCH, 256, 0, stream>>>(x, W, theta, out, partial);
    mpjrd_finalize_kernel<<<N / 256, 256, 0, stream>>>(partial, theta, r_hat, out);
}